// Round 7
// baseline (138.494 us; speedup 1.0000x reference)
//
#include <hip/hip_runtime.h>
#include <math.h>

// Fixed-size problem: B = 4194304
#define BTOT 4194304
#define TPB  256
#define EPT  16                 // elements per thread
#define CS   (TPB * EPT)        // 4096 elements per chunk/block
#define NCH  (BTOT / CS)        // 1024 chunks
#define CPT  (NCH / TPB)        // 4 chunks per thread in the chunk-scan

// ws layout (floats): 9 arrays of NCH chunk summaries
//  0:Pv 1:Sv 2:Pa 3:Sa 4:sL 5:sq 6:sL2 7:sLq 8:sq2

__constant__ const float kG  = 0.99f;
__constant__ const float kGT = 0.99f * 0.95f;

// ---- single-writer/single-reader sync state (device globals persist across
// graph replays; generation scheme keeps them self-consistent) ----
__device__ float    g_carr[2 * NCH];   // Cv,Ca carry INTO each chunk
__device__ float    g_mi[2];           // mean, inv_std
__device__ unsigned g_flag[NCH];       // per-chunk publish flag (= gen+1)
__device__ unsigned g_done = 0;        // generation / release flag

// Write-through agent-scope relaxed atomics: visible at the coherence point
// once vmcnt drains — NO cache-maintenance ops (r4/r5 validated: acquire/
// release fences at agent scope cost ~100 µs in L2 invalidates; this path
// doesn't).
__device__ __forceinline__ void st_ws(float* p, float x) {
    __hip_atomic_store(p, x, __ATOMIC_RELAXED, __HIP_MEMORY_SCOPE_AGENT);
}
__device__ __forceinline__ float ld_ws(const float* p) {
    return __hip_atomic_load(p, __ATOMIC_RELAXED, __HIP_MEMORY_SCOPE_AGENT);
}
__device__ __forceinline__ void st_u(unsigned* p, unsigned x) {
    __hip_atomic_store(p, x, __ATOMIC_RELAXED, __HIP_MEMORY_SCOPE_AGENT);
}
__device__ __forceinline__ unsigned ld_u(const unsigned* p) {
    return __hip_atomic_load(p, __ATOMIC_RELAXED, __HIP_MEMORY_SCOPE_AGENT);
}

__device__ __forceinline__ float wave_redf(float x) {
#pragma unroll
    for (int o = 32; o > 0; o >>= 1) x += __shfl_down(x, o);
    return x;
}
__device__ __forceinline__ double wave_redd(double x) {
#pragma unroll
    for (int o = 32; o > 0; o >>= 1) x += __shfl_down(x, o);
    return x;
}

// Hillis-Steele suffix scan over the block on affine pairs (P,S) for both
// recurrences. Entry j ends as the composition of threads j..TPB-1.
__device__ __forceinline__ void block_suffix_scan(
    float pv, float sv, float pa, float sa,
    float* lpv, float* lsv, float* lpa, float* lsa, int j)
{
    lpv[j] = pv; lsv[j] = sv; lpa[j] = pa; lsa[j] = sa;
    __syncthreads();
#pragma unroll
    for (int d = 1; d < TPB; d <<= 1) {
        float cpv = lpv[j], csv = lsv[j], cpa = lpa[j], csa = lsa[j];
        bool has = (j + d) < TPB;
        float qpv = 1.0f, qsv = 0.0f, qpa = 1.0f, qsa = 0.0f;
        if (has) { qpv = lpv[j+d]; qsv = lsv[j+d]; qpa = lpa[j+d]; qsa = lsa[j+d]; }
        __syncthreads();
        if (has) {
            lpv[j] = cpv * qpv; lsv[j] = csv + cpv * qsv;
            lpa[j] = cpa * qpa; lsa[j] = csa + cpa * qsa;
        }
        __syncthreads();
    }
}

// ============ Fused single-pass kernel, NO all-to-all barrier ==============
// Every block: publish 36 B summary + flag (single-writer).
// Block 0 only: poll 1024 flags (single-reader, zero RMW contention), scan
//   the summaries ONCE, publish 1024 carries + mean/inv, flip g_done.
// All blocks: relaxed spin on g_done (read-only broadcast), read 24 B back,
//   finalize from LDS-parked rr/dd.
__global__ __launch_bounds__(TPB) void ppo_fused(
    const float* __restrict__ r, const float* __restrict__ v,
    const int* __restrict__ mk, float* __restrict__ ws,
    float* __restrict__ outA, float* __restrict__ outV)
{
    const int c = blockIdx.x;
    const int j = threadIdx.x;
    const int base = c * CS + j * EPT;

    __shared__ float lpv[TPB], lsv[TPB], lpa[TPB], lsa[TPB];
    __shared__ float rb[4][5];
    __shared__ double rd[4][2];
    __shared__ float bcast[4];   // 0:carryV 1:carryA 2:mean 3:inv_std
    __shared__ float s_rr[EPT * TPB];   // [k][j] transposed: bank = j%32
    __shared__ float s_dd[EPT * TPB];
    __shared__ unsigned s_gen;

    if (j == 0) s_gen = ld_u(&g_done);   // per-launch generation baseline

    // ---------------- phase 1: load + summarize (inputs read ONCE) ---------
    unsigned mb = 0;             // mask bits packed: bit k = mask[base+k]
    {
        float rr[EPT], vv[EPT + 1], dd[EPT];
        int mm[EPT];
        const float4* r4 = (const float4*)(r + base);
        const float4* v4 = (const float4*)(v + base);
        const int4*   m4 = (const int4*)(mk + base);
#pragma unroll
        for (int k = 0; k < EPT / 4; ++k) {
            float4 a = r4[k];
            rr[4*k] = a.x; rr[4*k+1] = a.y; rr[4*k+2] = a.z; rr[4*k+3] = a.w;
            float4 b = v4[k];
            vv[4*k] = b.x; vv[4*k+1] = b.y; vv[4*k+2] = b.z; vv[4*k+3] = b.w;
            int4 m = m4[k];
            mm[4*k] = m.x; mm[4*k+1] = m.y; mm[4*k+2] = m.z; mm[4*k+3] = m.w;
        }
        vv[EPT] = (base + EPT < BTOT) ? v[base + EPT] : 0.0f;
#pragma unroll
        for (int k = 0; k < EPT; ++k) {
            mb |= ((unsigned)(mm[k] & 1)) << k;
            float m = (float)mm[k];
            dd[k] = rr[k] + kG * m * vv[k + 1] - vv[k];
        }
        // park rr/dd in LDS for phase 3 (own slots only; no sync needed)
#pragma unroll
        for (int k = 0; k < EPT; ++k) {
            s_rr[k * TPB + j] = rr[k];
            s_dd[k * TPB + j] = dd[k];
        }

        float pv = 1.0f, sv = 0.0f, pa = 1.0f, sa = 0.0f;
#pragma unroll
        for (int k = EPT - 1; k >= 0; --k) {
            float m = (float)mm[k];
            float av = kG * m, aa = kGT * m;
            sv = rr[k] + av * sv;
            sa = dd[k] + aa * sa;
            pv *= av; pa *= aa;
        }
        block_suffix_scan(pv, sv, pa, sa, lpv, lsv, lpa, lsa, j);
    }

    // per-thread carries within the block (4 regs live across the wait)
    float CinV = (j + 1 < TPB) ? lsv[j + 1] : 0.0f;
    float QrV  = (j + 1 < TPB) ? lpv[j + 1] : 1.0f;
    float CinA = (j + 1 < TPB) ? lsa[j + 1] : 0.0f;
    float QrA  = (j + 1 < TPB) ? lpa[j + 1] : 1.0f;

    // chunk-local A values + quadratic stats, then publish summary + flag
    {
        float x = CinA, ql = 1.0f;
        float s0 = 0, s1 = 0, s2 = 0, s3 = 0, s4 = 0;
#pragma unroll
        for (int k = EPT - 1; k >= 0; --k) {
            float m = (float)((mb >> k) & 1u);
            float aa = kGT * m;
            x = s_dd[k * TPB + j] + aa * x;
            ql *= aa;
            float q = ql * QrA;
            s0 += x; s1 += q; s2 += x * x; s3 += x * q; s4 += q * q;
        }
        s0 = wave_redf(s0); s1 = wave_redf(s1); s2 = wave_redf(s2);
        s3 = wave_redf(s3); s4 = wave_redf(s4);
        int wid = j >> 6, ln = j & 63;
        if (ln == 0) { rb[wid][0]=s0; rb[wid][1]=s1; rb[wid][2]=s2; rb[wid][3]=s3; rb[wid][4]=s4; }
        __syncthreads();
        if (j == 0) {
            float t0=0,t1=0,t2=0,t3=0,t4=0;
            for (int w = 0; w < 4; ++w) { t0+=rb[w][0]; t1+=rb[w][1]; t2+=rb[w][2]; t3+=rb[w][3]; t4+=rb[w][4]; }
            st_ws(&ws[0*NCH+c], lpv[0]); st_ws(&ws[1*NCH+c], lsv[0]);
            st_ws(&ws[2*NCH+c], lpa[0]); st_ws(&ws[3*NCH+c], lsa[0]);
            st_ws(&ws[4*NCH+c], t0);     st_ws(&ws[5*NCH+c], t1);
            st_ws(&ws[6*NCH+c], t2);     st_ws(&ws[7*NCH+c], t3);
            st_ws(&ws[8*NCH+c], t4);
            // drain write-through stores (waitcnt only), then raise our flag
            __builtin_amdgcn_fence(__ATOMIC_RELEASE, "workgroup");
            st_u(&g_flag[c], s_gen + 1u);
        }
    }

    // -------- designated block: the one-and-only chunk-summary scan --------
    if (c == 0) {
        const unsigned want = s_gen + 1u;   // s_gen valid: syncthreads passed
        // poll 1024 single-writer flags; thread j owns chunks 4j..4j+3
#pragma unroll
        for (int i = 0; i < CPT; ++i) {
            while (ld_u(&g_flag[4*j + i]) != want) __builtin_amdgcn_s_sleep(1);
        }
        __syncthreads();   // all summaries published & visible

        float cpv[CPT], csv[CPT], cpa[CPT], csa[CPT];
#pragma unroll
        for (int i = 0; i < CPT; ++i) {
            cpv[i] = ld_ws(ws + 0*NCH + 4*j + i);
            csv[i] = ld_ws(ws + 1*NCH + 4*j + i);
            cpa[i] = ld_ws(ws + 2*NCH + 4*j + i);
            csa[i] = ld_ws(ws + 3*NCH + 4*j + i);
        }
        float gpv = 1.0f, gsv = 0.0f, gpa = 1.0f, gsa = 0.0f;
#pragma unroll
        for (int i = CPT - 1; i >= 0; --i) {
            gsv = csv[i] + cpv[i] * gsv; gpv = cpv[i] * gpv;
            gsa = csa[i] + cpa[i] * gsa; gpa = cpa[i] * gpa;
        }
        block_suffix_scan(gpv, gsv, gpa, gsa, lpv, lsv, lpa, lsa, j);

        float Cv = (j + 1 < TPB) ? lsv[j + 1] : 0.0f;
        float Ca = (j + 1 < TPB) ? lsa[j + 1] : 0.0f;

        float sLv[CPT], sqv[CPT], sL2v[CPT], sLqv[CPT], sq2v[CPT];
#pragma unroll
        for (int i = 0; i < CPT; ++i) {
            sLv[i]  = ld_ws(ws + 4*NCH + 4*j + i);
            sqv[i]  = ld_ws(ws + 5*NCH + 4*j + i);
            sL2v[i] = ld_ws(ws + 6*NCH + 4*j + i);
            sLqv[i] = ld_ws(ws + 7*NCH + 4*j + i);
            sq2v[i] = ld_ws(ws + 8*NCH + 4*j + i);
        }
        double dS = 0.0, dS2 = 0.0;
#pragma unroll
        for (int i = CPT - 1; i >= 0; --i) {
            int g = 4*j + i;
            st_ws(&g_carr[2*g],     Cv);   // carry INTO chunk g
            st_ws(&g_carr[2*g + 1], Ca);
            dS  += (double)(sLv[i]  + Ca * sqv[i]);
            dS2 += (double)(sL2v[i] + 2.0f * Ca * sLqv[i] + Ca * Ca * sq2v[i]);
            Cv = csv[i] + cpv[i] * Cv;
            Ca = csa[i] + cpa[i] * Ca;
        }
        dS = wave_redd(dS); dS2 = wave_redd(dS2);
        int wid = j >> 6, ln = j & 63;
        if (ln == 0) { rd[wid][0] = dS; rd[wid][1] = dS2; }
        __syncthreads();   // drains ALL threads' g_carr stores (vmcnt @ barrier)
        if (j == 0) {
            double S  = rd[0][0] + rd[1][0] + rd[2][0] + rd[3][0];
            double S2 = rd[0][1] + rd[1][1] + rd[2][1] + rd[3][1];
            double n = (double)BTOT;
            double m_ = S / n;
            double var = (S2 - S * m_) / (n - 1.0);   // ddof=1
            st_ws(&g_mi[0], (float)m_);
            st_ws(&g_mi[1], (float)(1.0 / sqrt(var)));
            __builtin_amdgcn_fence(__ATOMIC_RELEASE, "workgroup");
            st_u(&g_done, want);   // release broadcast
        }
    }

    // -------- all blocks: wait for release, read carry + mean/inv ----------
    if (j == 0) {
        const unsigned want = s_gen + 1u;
        while (ld_u(&g_done) != want) __builtin_amdgcn_s_sleep(8);
        bcast[0] = ld_ws(&g_carr[2*c]);
        bcast[1] = ld_ws(&g_carr[2*c + 1]);
        bcast[2] = ld_ws(&g_mi[0]);
        bcast[3] = ld_ws(&g_mi[1]);
    }
    __syncthreads();

    const float Ccv  = bcast[0];
    const float Cca  = bcast[1];
    const float mean = bcast[2];
    const float inv  = bcast[3];

    // ------- phase 3: finalize from LDS (no input re-read) -----------------
    float xv = CinV + QrV * Ccv;
    float xa = CinA + QrA * Cca;
    float oA[EPT], oV[EPT];
#pragma unroll
    for (int k = EPT - 1; k >= 0; --k) {
        float m = (float)((mb >> k) & 1u);
        xv = s_rr[k * TPB + j] + kG  * m * xv;
        xa = s_dd[k * TPB + j] + kGT * m * xa;
        oV[k] = xv;
        oA[k] = (xa - mean) * inv;
    }
    float4* a4 = (float4*)(outA + base);
    float4* w4 = (float4*)(outV + base);
#pragma unroll
    for (int k = 0; k < EPT / 4; ++k) {
        a4[k] = make_float4(oA[4*k], oA[4*k+1], oA[4*k+2], oA[4*k+3]);
        w4[k] = make_float4(oV[4*k], oV[4*k+1], oV[4*k+2], oV[4*k+3]);
    }
}

// =================== Fallback path: r0-style K1 + K2 (proven 32.6 µs) ======
__global__ __launch_bounds__(TPB) void ppo_k1_summarize(
    const float* __restrict__ r, const float* __restrict__ v,
    const int* __restrict__ mk, float* __restrict__ ws) {
    const int c = blockIdx.x;
    const int j = threadIdx.x;
    const int base = c * CS + j * EPT;

    float rr[EPT], vv[EPT + 1], dd[EPT];
    int mm[EPT];
    const float4* r4 = (const float4*)(r + base);
    const float4* v4 = (const float4*)(v + base);
    const int4*   m4 = (const int4*)(mk + base);
#pragma unroll
    for (int k = 0; k < EPT / 4; ++k) {
        float4 a = r4[k];
        rr[4*k] = a.x; rr[4*k+1] = a.y; rr[4*k+2] = a.z; rr[4*k+3] = a.w;
        float4 b = v4[k];
        vv[4*k] = b.x; vv[4*k+1] = b.y; vv[4*k+2] = b.z; vv[4*k+3] = b.w;
        int4 m = m4[k];
        mm[4*k] = m.x; mm[4*k+1] = m.y; mm[4*k+2] = m.z; mm[4*k+3] = m.w;
    }
    vv[EPT] = (base + EPT < BTOT) ? v[base + EPT] : 0.0f;

#pragma unroll
    for (int k = 0; k < EPT; ++k) {
        float m = (float)mm[k];
        dd[k] = rr[k] + kG * m * vv[k + 1] - vv[k];
    }

    float pv = 1.0f, sv = 0.0f, pa = 1.0f, sa = 0.0f;
#pragma unroll
    for (int k = EPT - 1; k >= 0; --k) {
        float m = (float)mm[k];
        float av = kG * m, aa = kGT * m;
        sv = rr[k] + av * sv;
        sa = dd[k] + aa * sa;
        pv *= av; pa *= aa;
    }

    __shared__ float lpv[TPB], lsv[TPB], lpa[TPB], lsa[TPB];
    block_suffix_scan(pv, sv, pa, sa, lpv, lsv, lpa, lsa, j);

    float CinA = (j + 1 < TPB) ? lsa[j + 1] : 0.0f;
    float QrA  = (j + 1 < TPB) ? lpa[j + 1] : 1.0f;
    float chPv = lpv[0], chSv = lsv[0], chPa = lpa[0], chSa = lsa[0];

    float x = CinA, ql = 1.0f;
    float s0 = 0, s1 = 0, s2 = 0, s3 = 0, s4 = 0;
#pragma unroll
    for (int k = EPT - 1; k >= 0; --k) {
        float m = (float)mm[k];
        float aa = kGT * m;
        x = dd[k] + aa * x;
        ql *= aa;
        float q = ql * QrA;
        s0 += x; s1 += q; s2 += x * x; s3 += x * q; s4 += q * q;
    }
    s0 = wave_redf(s0); s1 = wave_redf(s1); s2 = wave_redf(s2);
    s3 = wave_redf(s3); s4 = wave_redf(s4);
    __shared__ float rb[4][5];
    int wid = j >> 6, ln = j & 63;
    if (ln == 0) { rb[wid][0]=s0; rb[wid][1]=s1; rb[wid][2]=s2; rb[wid][3]=s3; rb[wid][4]=s4; }
    __syncthreads();
    if (j == 0) {
        float t0=0,t1=0,t2=0,t3=0,t4=0;
        for (int w = 0; w < 4; ++w) { t0+=rb[w][0]; t1+=rb[w][1]; t2+=rb[w][2]; t3+=rb[w][3]; t4+=rb[w][4]; }
        ws[0*NCH+c] = chPv; ws[1*NCH+c] = chSv; ws[2*NCH+c] = chPa; ws[3*NCH+c] = chSa;
        ws[4*NCH+c] = t0;   ws[5*NCH+c] = t1;   ws[6*NCH+c] = t2;
        ws[7*NCH+c] = t3;   ws[8*NCH+c] = t4;
    }
}

__global__ __launch_bounds__(TPB) void ppo_k2_finalize(
    const float* __restrict__ r, const float* __restrict__ v,
    const int* __restrict__ mk, const float* __restrict__ ws,
    float* __restrict__ outA, float* __restrict__ outV)
{
    const int c = blockIdx.x;
    const int j = threadIdx.x;
    const int base = c * CS + j * EPT;

    __shared__ float lpv[TPB], lsv[TPB], lpa[TPB], lsa[TPB];
    __shared__ double rd[4][2];
    __shared__ float bcast[4];

    {
        float cpv[CPT], csv[CPT], cpa[CPT], csa[CPT];
        {
            float4 t;
            t = *(const float4*)(ws + 0*NCH + 4*j); cpv[0]=t.x; cpv[1]=t.y; cpv[2]=t.z; cpv[3]=t.w;
            t = *(const float4*)(ws + 1*NCH + 4*j); csv[0]=t.x; csv[1]=t.y; csv[2]=t.z; csv[3]=t.w;
            t = *(const float4*)(ws + 2*NCH + 4*j); cpa[0]=t.x; cpa[1]=t.y; cpa[2]=t.z; cpa[3]=t.w;
            t = *(const float4*)(ws + 3*NCH + 4*j); csa[0]=t.x; csa[1]=t.y; csa[2]=t.z; csa[3]=t.w;
        }
        float gpv = 1.0f, gsv = 0.0f, gpa = 1.0f, gsa = 0.0f;
#pragma unroll
        for (int i = CPT - 1; i >= 0; --i) {
            gsv = csv[i] + cpv[i] * gsv; gpv = cpv[i] * gpv;
            gsa = csa[i] + cpa[i] * gsa; gpa = cpa[i] * gpa;
        }

        block_suffix_scan(gpv, gsv, gpa, gsa, lpv, lsv, lpa, lsa, j);

        float Cv = (j + 1 < TPB) ? lsv[j + 1] : 0.0f;
        float Ca = (j + 1 < TPB) ? lsa[j + 1] : 0.0f;

        float sLv[CPT], sqv[CPT], sL2v[CPT], sLqv[CPT], sq2v[CPT];
        {
            float4 t;
            t = *(const float4*)(ws + 4*NCH + 4*j); sLv[0]=t.x;  sLv[1]=t.y;  sLv[2]=t.z;  sLv[3]=t.w;
            t = *(const float4*)(ws + 5*NCH + 4*j); sqv[0]=t.x;  sqv[1]=t.y;  sqv[2]=t.z;  sqv[3]=t.w;
            t = *(const float4*)(ws + 6*NCH + 4*j); sL2v[0]=t.x; sL2v[1]=t.y; sL2v[2]=t.z; sL2v[3]=t.w;
            t = *(const float4*)(ws + 7*NCH + 4*j); sLqv[0]=t.x; sLqv[1]=t.y; sLqv[2]=t.z; sLqv[3]=t.w;
            t = *(const float4*)(ws + 8*NCH + 4*j); sq2v[0]=t.x; sq2v[1]=t.y; sq2v[2]=t.z; sq2v[3]=t.w;
        }
        double dS = 0.0, dS2 = 0.0;
#pragma unroll
        for (int i = CPT - 1; i >= 0; --i) {
            int g = 4*j + i;
            if (g == c) { bcast[0] = Cv; bcast[1] = Ca; }
            dS  += (double)(sLv[i]  + Ca * sqv[i]);
            dS2 += (double)(sL2v[i] + 2.0f * Ca * sLqv[i] + Ca * Ca * sq2v[i]);
            Cv = csv[i] + cpv[i] * Cv;
            Ca = csa[i] + cpa[i] * Ca;
        }
        dS = wave_redd(dS); dS2 = wave_redd(dS2);
        int wid = j >> 6, ln = j & 63;
        if (ln == 0) { rd[wid][0] = dS; rd[wid][1] = dS2; }
        __syncthreads();
        if (j == 0) {
            double S  = rd[0][0] + rd[1][0] + rd[2][0] + rd[3][0];
            double S2 = rd[0][1] + rd[1][1] + rd[2][1] + rd[3][1];
            double n = (double)BTOT;
            double mean = S / n;
            double var = (S2 - S * mean) / (n - 1.0);
            bcast[2] = (float)mean;
            bcast[3] = (float)(1.0 / sqrt(var));
        }
        __syncthreads();
    }

    float rr[EPT], vv[EPT + 1], dd[EPT];
    int mm[EPT];
    const float4* r4 = (const float4*)(r + base);
    const float4* v4 = (const float4*)(v + base);
    const int4*   m4 = (const int4*)(mk + base);
#pragma unroll
    for (int k = 0; k < EPT / 4; ++k) {
        float4 a = r4[k];
        rr[4*k] = a.x; rr[4*k+1] = a.y; rr[4*k+2] = a.z; rr[4*k+3] = a.w;
        float4 b = v4[k];
        vv[4*k] = b.x; vv[4*k+1] = b.y; vv[4*k+2] = b.z; vv[4*k+3] = b.w;
        int4 m = m4[k];
        mm[4*k] = m.x; mm[4*k+1] = m.y; mm[4*k+2] = m.z; mm[4*k+3] = m.w;
    }
    vv[EPT] = (base + EPT < BTOT) ? v[base + EPT] : 0.0f;
#pragma unroll
    for (int k = 0; k < EPT; ++k) {
        float m = (float)mm[k];
        dd[k] = rr[k] + kG * m * vv[k + 1] - vv[k];
    }

    float pv = 1.0f, sv = 0.0f, pa = 1.0f, sa = 0.0f;
#pragma unroll
    for (int k = EPT - 1; k >= 0; --k) {
        float m = (float)mm[k];
        float av = kG * m, aa = kGT * m;
        sv = rr[k] + av * sv;
        sa = dd[k] + aa * sa;
        pv *= av; pa *= aa;
    }
    block_suffix_scan(pv, sv, pa, sa, lpv, lsv, lpa, lsa, j);

    float CinV = (j + 1 < TPB) ? lsv[j + 1] : 0.0f;
    float QrV  = (j + 1 < TPB) ? lpv[j + 1] : 1.0f;
    float CinA = (j + 1 < TPB) ? lsa[j + 1] : 0.0f;
    float QrA  = (j + 1 < TPB) ? lpa[j + 1] : 1.0f;

    const float Ccv  = bcast[0];
    const float Cca  = bcast[1];
    const float mean = bcast[2];
    const float inv  = bcast[3];

    float xv = CinV + QrV * Ccv;
    float xa = CinA + QrA * Cca;
    float oA[EPT], oV[EPT];
#pragma unroll
    for (int k = EPT - 1; k >= 0; --k) {
        float m = (float)mm[k];
        xv = rr[k] + kG  * m * xv;
        xa = dd[k] + kGT * m * xa;
        oV[k] = xv;
        oA[k] = (xa - mean) * inv;
    }
    float4* a4 = (float4*)(outA + base);
    float4* w4 = (float4*)(outV + base);
#pragma unroll
    for (int k = 0; k < EPT / 4; ++k) {
        a4[k] = make_float4(oA[4*k], oA[4*k+1], oA[4*k+2], oA[4*k+3]);
        w4[k] = make_float4(oV[4*k], oV[4*k+1], oV[4*k+2], oV[4*k+3]);
    }
}

extern "C" void kernel_launch(void* const* d_in, const int* in_sizes, int n_in,
                              void* d_out, int out_size, void* d_ws, size_t ws_size,
                              hipStream_t stream) {
    const float* r  = (const float*)d_in[0];
    const float* v  = (const float*)d_in[1];
    const int*   mk = (const int*)d_in[2];
    float* outA = (float*)d_out;
    float* outV = outA + BTOT;
    float* ws   = (float*)d_ws;

    void* args[6];
    args[0] = (void*)&r;    args[1] = (void*)&v;    args[2] = (void*)&mk;
    args[3] = (void*)&ws;   args[4] = (void*)&outA; args[5] = (void*)&outV;

    // Cooperative launch guarantees all 1024 blocks are co-resident (4/CU at
    // 37 KB LDS) — required so the flag/spin protocol cannot deadlock.
    hipError_t e = hipLaunchCooperativeKernel(
        (const void*)ppo_fused, dim3(NCH), dim3(TPB), args, 0, stream);
    if (e != hipSuccess) {
        hipLaunchKernelGGL(ppo_k1_summarize, dim3(NCH), dim3(TPB), 0, stream,
                           r, v, mk, ws);
        hipLaunchKernelGGL(ppo_k2_finalize, dim3(NCH), dim3(TPB), 0, stream,
                           r, v, mk, ws, outA, outV);
    }
}

// Round 8
// 116.714 us; speedup vs baseline: 1.1866x; 1.1866x over previous
//
#include <hip/hip_runtime.h>
#include <math.h>

// Fixed-size problem: B = 4194304
#define BTOT 4194304
#define TPB  256
#define EPT  16                 // elements per thread
#define CS   (TPB * EPT)        // 4096 elements per chunk/block
#define NCH  (BTOT / CS)        // 1024 chunks
#define CPT  (NCH / TPB)        // 4 chunks per thread in the chunk-scan

// ws layout (floats): 9 arrays of NCH chunk summaries
//  0:Pv 1:Sv 2:Pa 3:Sa 4:sL 5:sq 6:sL2 7:sLq 8:sq2

__constant__ const float kG  = 0.99f;
__constant__ const float kGT = 0.99f * 0.95f;

__device__ __forceinline__ float wave_redf(float x) {
#pragma unroll
    for (int o = 32; o > 0; o >>= 1) x += __shfl_down(x, o);
    return x;
}
__device__ __forceinline__ double wave_redd(double x) {
#pragma unroll
    for (int o = 32; o > 0; o >>= 1) x += __shfl_down(x, o);
    return x;
}

// Hillis-Steele suffix scan over the block on affine pairs (P,S) for both
// recurrences. Entry j ends as the composition of threads j..TPB-1.
__device__ __forceinline__ void block_suffix_scan(
    float pv, float sv, float pa, float sa,
    float* lpv, float* lsv, float* lpa, float* lsa, int j)
{
    lpv[j] = pv; lsv[j] = sv; lpa[j] = pa; lsa[j] = sa;
    __syncthreads();
#pragma unroll
    for (int d = 1; d < TPB; d <<= 1) {
        float cpv = lpv[j], csv = lsv[j], cpa = lpa[j], csa = lsa[j];
        bool has = (j + d) < TPB;
        float qpv = 1.0f, qsv = 0.0f, qpa = 1.0f, qsa = 0.0f;
        if (has) { qpv = lpv[j+d]; qsv = lsv[j+d]; qpa = lpa[j+d]; qsa = lsa[j+d]; }
        __syncthreads();
        if (has) {
            lpv[j] = cpv * qpv; lsv[j] = csv + cpv * qsv;
            lpa[j] = cpa * qpa; lsa[j] = csa + cpa * qsa;
        }
        __syncthreads();
    }
}

// ---------------- K1: per-chunk affine summaries + quadratic stats ---------
__global__ __launch_bounds__(TPB) void ppo_k1_summarize(
    const float* __restrict__ r, const float* __restrict__ v,
    const int* __restrict__ mk, float* __restrict__ ws) {
    const int c = blockIdx.x;
    const int j = threadIdx.x;
    const int base = c * CS + j * EPT;

    float rr[EPT], vv[EPT + 1], dd[EPT];
    int mm[EPT];
    const float4* r4 = (const float4*)(r + base);
    const float4* v4 = (const float4*)(v + base);
    const int4*   m4 = (const int4*)(mk + base);
#pragma unroll
    for (int k = 0; k < EPT / 4; ++k) {
        float4 a = r4[k];
        rr[4*k] = a.x; rr[4*k+1] = a.y; rr[4*k+2] = a.z; rr[4*k+3] = a.w;
        float4 b = v4[k];
        vv[4*k] = b.x; vv[4*k+1] = b.y; vv[4*k+2] = b.z; vv[4*k+3] = b.w;
        int4 m = m4[k];
        mm[4*k] = m.x; mm[4*k+1] = m.y; mm[4*k+2] = m.z; mm[4*k+3] = m.w;
    }
    vv[EPT] = (base + EPT < BTOT) ? v[base + EPT] : 0.0f;

#pragma unroll
    for (int k = 0; k < EPT; ++k) {
        float m = (float)mm[k];
        dd[k] = rr[k] + kG * m * vv[k + 1] - vv[k];
    }

    // per-thread affine summaries (reverse, zero carry)
    float pv = 1.0f, sv = 0.0f, pa = 1.0f, sa = 0.0f;
#pragma unroll
    for (int k = EPT - 1; k >= 0; --k) {
        float m = (float)mm[k];
        float av = kG * m, aa = kGT * m;
        sv = rr[k] + av * sv;
        sa = dd[k] + aa * sa;
        pv *= av; pa *= aa;
    }

    __shared__ float lpv[TPB], lsv[TPB], lpa[TPB], lsa[TPB];
    block_suffix_scan(pv, sv, pa, sa, lpv, lsv, lpa, lsa, j);

    float CinA = (j + 1 < TPB) ? lsa[j + 1] : 0.0f;
    float QrA  = (j + 1 < TPB) ? lpa[j + 1] : 1.0f;
    float chPv = lpv[0], chSv = lsv[0], chPa = lpa[0], chSa = lsa[0];

    // chunk-local A values + quadratic stats: A = L + q * C_chunk
    float x = CinA, ql = 1.0f;
    float s0 = 0, s1 = 0, s2 = 0, s3 = 0, s4 = 0;
#pragma unroll
    for (int k = EPT - 1; k >= 0; --k) {
        float m = (float)mm[k];
        float aa = kGT * m;
        x = dd[k] + aa * x;
        ql *= aa;
        float q = ql * QrA;
        s0 += x; s1 += q; s2 += x * x; s3 += x * q; s4 += q * q;
    }
    s0 = wave_redf(s0); s1 = wave_redf(s1); s2 = wave_redf(s2);
    s3 = wave_redf(s3); s4 = wave_redf(s4);
    __shared__ float rb[4][5];
    int wid = j >> 6, ln = j & 63;
    if (ln == 0) { rb[wid][0]=s0; rb[wid][1]=s1; rb[wid][2]=s2; rb[wid][3]=s3; rb[wid][4]=s4; }
    __syncthreads();
    if (j == 0) {
        float t0=0,t1=0,t2=0,t3=0,t4=0;
        for (int w = 0; w < 4; ++w) { t0+=rb[w][0]; t1+=rb[w][1]; t2+=rb[w][2]; t3+=rb[w][3]; t4+=rb[w][4]; }
        ws[0*NCH+c] = chPv; ws[1*NCH+c] = chSv; ws[2*NCH+c] = chPa; ws[3*NCH+c] = chSa;
        ws[4*NCH+c] = t0;   ws[5*NCH+c] = t1;   ws[6*NCH+c] = t2;
        ws[7*NCH+c] = t3;   ws[8*NCH+c] = t4;
    }
}

// ------- K2: every block redundantly scans chunk summaries, then finalizes
//         its own chunk (inputs re-read from L3). No grid sync needed. -----
__global__ __launch_bounds__(TPB) void ppo_k2_finalize(
    const float* __restrict__ r, const float* __restrict__ v,
    const int* __restrict__ mk, const float* __restrict__ ws,
    float* __restrict__ outA, float* __restrict__ outV)
{
    const int c = blockIdx.x;
    const int j = threadIdx.x;
    const int base = c * CS + j * EPT;

    __shared__ float lpv[TPB], lsv[TPB], lpa[TPB], lsa[TPB];
    __shared__ double rd[4][2];
    __shared__ float bcast[4];   // 0:carryV(into chunk c) 1:carryA 2:mean 3:inv_std

    // ---- redundant chunk-summary scan (identical in every block) ----
    {
        float cpv[CPT], csv[CPT], cpa[CPT], csa[CPT];
        {
            float4 t;
            t = *(const float4*)(ws + 0*NCH + 4*j); cpv[0]=t.x; cpv[1]=t.y; cpv[2]=t.z; cpv[3]=t.w;
            t = *(const float4*)(ws + 1*NCH + 4*j); csv[0]=t.x; csv[1]=t.y; csv[2]=t.z; csv[3]=t.w;
            t = *(const float4*)(ws + 2*NCH + 4*j); cpa[0]=t.x; cpa[1]=t.y; cpa[2]=t.z; cpa[3]=t.w;
            t = *(const float4*)(ws + 3*NCH + 4*j); csa[0]=t.x; csa[1]=t.y; csa[2]=t.z; csa[3]=t.w;
        }
        float gpv = 1.0f, gsv = 0.0f, gpa = 1.0f, gsa = 0.0f;
#pragma unroll
        for (int i = CPT - 1; i >= 0; --i) {
            gsv = csv[i] + cpv[i] * gsv; gpv = cpv[i] * gpv;
            gsa = csa[i] + cpa[i] * gsa; gpa = cpa[i] * gpa;
        }

        block_suffix_scan(gpv, gsv, gpa, gsa, lpv, lsv, lpa, lsa, j);

        float Cv = (j + 1 < TPB) ? lsv[j + 1] : 0.0f;
        float Ca = (j + 1 < TPB) ? lsa[j + 1] : 0.0f;

        float sLv[CPT], sqv[CPT], sL2v[CPT], sLqv[CPT], sq2v[CPT];
        {
            float4 t;
            t = *(const float4*)(ws + 4*NCH + 4*j); sLv[0]=t.x;  sLv[1]=t.y;  sLv[2]=t.z;  sLv[3]=t.w;
            t = *(const float4*)(ws + 5*NCH + 4*j); sqv[0]=t.x;  sqv[1]=t.y;  sqv[2]=t.z;  sqv[3]=t.w;
            t = *(const float4*)(ws + 6*NCH + 4*j); sL2v[0]=t.x; sL2v[1]=t.y; sL2v[2]=t.z; sL2v[3]=t.w;
            t = *(const float4*)(ws + 7*NCH + 4*j); sLqv[0]=t.x; sLqv[1]=t.y; sLqv[2]=t.z; sLqv[3]=t.w;
            t = *(const float4*)(ws + 8*NCH + 4*j); sq2v[0]=t.x; sq2v[1]=t.y; sq2v[2]=t.z; sq2v[3]=t.w;
        }
        double dS = 0.0, dS2 = 0.0;
#pragma unroll
        for (int i = CPT - 1; i >= 0; --i) {
            int g = 4*j + i;
            if (g == c) { bcast[0] = Cv; bcast[1] = Ca; }   // carry INTO our chunk
            dS  += (double)(sLv[i]  + Ca * sqv[i]);
            dS2 += (double)(sL2v[i] + 2.0f * Ca * sLqv[i] + Ca * Ca * sq2v[i]);
            Cv = csv[i] + cpv[i] * Cv;
            Ca = csa[i] + cpa[i] * Ca;
        }
        dS = wave_redd(dS); dS2 = wave_redd(dS2);
        int wid = j >> 6, ln = j & 63;
        if (ln == 0) { rd[wid][0] = dS; rd[wid][1] = dS2; }
        __syncthreads();
        if (j == 0) {
            double S  = rd[0][0] + rd[1][0] + rd[2][0] + rd[3][0];
            double S2 = rd[0][1] + rd[1][1] + rd[2][1] + rd[3][1];
            double n = (double)BTOT;
            double mean = S / n;
            double var = (S2 - S * mean) / (n - 1.0);   // ddof=1
            bcast[2] = (float)mean;
            bcast[3] = (float)(1.0 / sqrt(var));
        }
        __syncthreads();
    }

    // ---- finalize this block's chunk (inputs are L3-resident after K1) ----
    float rr[EPT], vv[EPT + 1], dd[EPT];
    int mm[EPT];
    const float4* r4 = (const float4*)(r + base);
    const float4* v4 = (const float4*)(v + base);
    const int4*   m4 = (const int4*)(mk + base);
#pragma unroll
    for (int k = 0; k < EPT / 4; ++k) {
        float4 a = r4[k];
        rr[4*k] = a.x; rr[4*k+1] = a.y; rr[4*k+2] = a.z; rr[4*k+3] = a.w;
        float4 b = v4[k];
        vv[4*k] = b.x; vv[4*k+1] = b.y; vv[4*k+2] = b.z; vv[4*k+3] = b.w;
        int4 m = m4[k];
        mm[4*k] = m.x; mm[4*k+1] = m.y; mm[4*k+2] = m.z; mm[4*k+3] = m.w;
    }
    vv[EPT] = (base + EPT < BTOT) ? v[base + EPT] : 0.0f;
#pragma unroll
    for (int k = 0; k < EPT; ++k) {
        float m = (float)mm[k];
        dd[k] = rr[k] + kG * m * vv[k + 1] - vv[k];
    }

    float pv = 1.0f, sv = 0.0f, pa = 1.0f, sa = 0.0f;
#pragma unroll
    for (int k = EPT - 1; k >= 0; --k) {
        float m = (float)mm[k];
        float av = kG * m, aa = kGT * m;
        sv = rr[k] + av * sv;
        sa = dd[k] + aa * sa;
        pv *= av; pa *= aa;
    }
    block_suffix_scan(pv, sv, pa, sa, lpv, lsv, lpa, lsa, j);

    float CinV = (j + 1 < TPB) ? lsv[j + 1] : 0.0f;
    float QrV  = (j + 1 < TPB) ? lpv[j + 1] : 1.0f;
    float CinA = (j + 1 < TPB) ? lsa[j + 1] : 0.0f;
    float QrA  = (j + 1 < TPB) ? lpa[j + 1] : 1.0f;

    const float Ccv  = bcast[0];
    const float Cca  = bcast[1];
    const float mean = bcast[2];
    const float inv  = bcast[3];

    float xv = CinV + QrV * Ccv;   // true value at this thread's right boundary
    float xa = CinA + QrA * Cca;
    float oA[EPT], oV[EPT];
#pragma unroll
    for (int k = EPT - 1; k >= 0; --k) {
        float m = (float)mm[k];
        xv = rr[k] + kG  * m * xv;
        xa = dd[k] + kGT * m * xa;
        oV[k] = xv;
        oA[k] = (xa - mean) * inv;
    }
    float4* a4 = (float4*)(outA + base);
    float4* w4 = (float4*)(outV + base);
#pragma unroll
    for (int k = 0; k < EPT / 4; ++k) {
        a4[k] = make_float4(oA[4*k], oA[4*k+1], oA[4*k+2], oA[4*k+3]);
        w4[k] = make_float4(oV[4*k], oV[4*k+1], oV[4*k+2], oV[4*k+3]);
    }
}

extern "C" void kernel_launch(void* const* d_in, const int* in_sizes, int n_in,
                              void* d_out, int out_size, void* d_ws, size_t ws_size,
                              hipStream_t stream) {
    const float* r  = (const float*)d_in[0];
    const float* v  = (const float*)d_in[1];
    const int*   mk = (const int*)d_in[2];
    float* outA = (float*)d_out;
    float* outV = outA + BTOT;
    float* ws   = (float*)d_ws;

    hipLaunchKernelGGL(ppo_k1_summarize, dim3(NCH), dim3(TPB), 0, stream,
                       r, v, mk, ws);
    hipLaunchKernelGGL(ppo_k2_finalize, dim3(NCH), dim3(TPB), 0, stream,
                       r, v, mk, ws, outA, outV);
}